// Round 2
// baseline (2783.894 us; speedup 1.0000x reference)
//
#include <hip/hip_runtime.h>

typedef unsigned short u16;
typedef unsigned int   u32;
typedef __attribute__((ext_vector_type(8))) short          short8;
typedef __attribute__((ext_vector_type(4))) float          f32x4;
typedef __attribute__((ext_vector_type(8))) unsigned short u16x8;
typedef __attribute__((ext_vector_type(4))) unsigned short u16x4;

#define T_SEQ  2048
#define DMODEL 1024
#define NHEAD  16
#define DHEAD  64
#define HBUF   4194304   // elems in one (B,H,T,DH) buffer = 2*16*2048*64

__device__ __forceinline__ float bf2f(u16 u) {
    u32 i = ((u32)u) << 16; float f; __builtin_memcpy(&f, &i, 4); return f;
}
__device__ __forceinline__ u16 f2bf(float f) {
    u32 x; __builtin_memcpy(&x, &f, 4);
    return (u16)((x + 0x7FFFu + ((x >> 16) & 1u)) >> 16);   // RNE
}

// ---------------- LayerNorm (f32 in -> bf16 out): one block per row of 1024 ----------------
__global__ __launch_bounds__(256) void ln_k(const float* __restrict__ x,
                                            const float* __restrict__ g,
                                            const float* __restrict__ bb,
                                            u16* __restrict__ out)
{
    int row = blockIdx.x, tid = threadIdx.x;
    const float* xr = x + (size_t)row * DMODEL;
    f32x4 v = *(const f32x4*)(xr + tid * 4);
    float s  = v[0] + v[1] + v[2] + v[3];
    float s2 = v[0]*v[0] + v[1]*v[1] + v[2]*v[2] + v[3]*v[3];
    #pragma unroll
    for (int o = 32; o; o >>= 1) { s += __shfl_xor(s, o); s2 += __shfl_xor(s2, o); }
    __shared__ float rs[4], rq[4];
    if ((tid & 63) == 0) { rs[tid >> 6] = s; rq[tid >> 6] = s2; }
    __syncthreads();
    float S  = rs[0] + rs[1] + rs[2] + rs[3];
    float S2 = rq[0] + rq[1] + rq[2] + rq[3];
    float mean = S * (1.f / DMODEL);
    float var  = S2 * (1.f / DMODEL) - mean * mean;
    float rstd = rsqrtf(var + 1e-5f);
    f32x4 gv = *(const f32x4*)(g + tid * 4);
    f32x4 bv = *(const f32x4*)(bb + tid * 4);
    u16x4 o;
    #pragma unroll
    for (int e = 0; e < 4; e++)
        o[e] = f2bf((v[e] - mean) * rstd * gv[e] + bv[e]);
    *(u16x4*)(out + (size_t)row * DMODEL + tid * 4) = o;
}

// -------- 64x64-tile transpose + f32->bf16 convert: out[c][r] = bf16(in[r][c]) --------
__global__ __launch_bounds__(256) void tr_k(const float* __restrict__ in,
                                            u16* __restrict__ out, int R, int C)
{
    __shared__ u16 s[64][72];
    int tid = threadIdx.x;
    int c0 = blockIdx.x * 64, r0 = blockIdx.y * 64;
    #pragma unroll
    for (int p = 0; p < 2; p++) {
        int r = (tid >> 3) + p * 32, cq = (tid & 7) * 8;
        const float* ip = in + (size_t)(r0 + r) * C + c0 + cq;
        f32x4 a = *(const f32x4*)ip;
        f32x4 b = *(const f32x4*)(ip + 4);
        u16x8 o;
        #pragma unroll
        for (int e = 0; e < 4; e++) { o[e] = f2bf(a[e]); o[4 + e] = f2bf(b[e]); }
        *(u16x8*)(&s[r][cq]) = o;
    }
    __syncthreads();
    int oc = tid >> 2, kq = (tid & 3) * 16;
    u16 tmp[16] __attribute__((aligned(16)));
    #pragma unroll
    for (int e = 0; e < 16; e++) tmp[e] = s[kq + e][oc];
    u16* op = out + (size_t)(c0 + oc) * R + r0 + kq;
    *(u16x8*)op       = *(const u16x8*)(&tmp[0]);
    *(u16x8*)(op + 8) = *(const u16x8*)(&tmp[8]);
}

// ---------------- MFMA GEMM: C = A[M,K] @ Bt[N,K]^T (bf16 in, f32 acc), fused epilogues ----------------
constexpr int EPI_QKV = 0, EPI_RESF = 1, EPI_GELU = 2, EPI_RES2 = 3;

template<int EPI>
__global__ __launch_bounds__(256) void gemm_k(
    const u16* __restrict__ A, const u16* __restrict__ Bt, void* __restrict__ outv,
    int M, int N, int K,
    const float* __restrict__ b0, const float* __restrict__ b1, const float* __restrict__ b2,
    const float* __restrict__ resid,
    const float* __restrict__ cosp, const float* __restrict__ sinp)
{
    __shared__ u16 As[128 * 40];
    __shared__ u16 Bs[128 * 40];
    int tid = threadIdx.x;
    int n0 = blockIdx.x * 128, m0 = blockIdx.y * 128;
    int wave = tid >> 6, lane = tid & 63, lm = lane & 15, ko = lane >> 4;
    int wm = (wave & 1) * 64, wn = (wave >> 1) * 64;
    f32x4 acc[4][4];
    #pragma unroll
    for (int i = 0; i < 4; i++)
        #pragma unroll
        for (int j = 0; j < 4; j++) acc[i][j] = (f32x4){0.f, 0.f, 0.f, 0.f};

    int sr = tid >> 2, sq = tid & 3;
    const u16* Ab = A  + (size_t)m0 * K;
    const u16* Bb = Bt + (size_t)n0 * K;

    for (int kt = 0; kt < K; kt += 32) {
        __syncthreads();
        #pragma unroll
        for (int p = 0; p < 2; p++) {
            int r = sr + p * 64;
            *(u16x8*)(&As[r * 40 + sq * 8]) = *(const u16x8*)(Ab + (size_t)r * K + kt + sq * 8);
            *(u16x8*)(&Bs[r * 40 + sq * 8]) = *(const u16x8*)(Bb + (size_t)r * K + kt + sq * 8);
        }
        __syncthreads();
        short8 af[4], bf[4];
        #pragma unroll
        for (int i = 0; i < 4; i++) af[i] = *(const short8*)(&As[(wm + i * 16 + lm) * 40 + ko * 8]);
        #pragma unroll
        for (int j = 0; j < 4; j++) bf[j] = *(const short8*)(&Bs[(wn + j * 16 + lm) * 40 + ko * 8]);
        #pragma unroll
        for (int i = 0; i < 4; i++)
            #pragma unroll
            for (int j = 0; j < 4; j++)
                acc[i][j] = __builtin_amdgcn_mfma_f32_16x16x32_bf16(af[i], bf[j], acc[i][j], 0, 0, 0);
    }

    // epilogue — C/D layout: col = lane&15, row = (lane>>4)*4 + reg  [m89/m91]
    #pragma unroll
    for (int i = 0; i < 4; i++) {
        #pragma unroll
        for (int j = 0; j < 4; j++) {
            int n = n0 + wn + j * 16 + lm;
            #pragma unroll
            for (int r = 0; r < 4; r++) {
                int m = m0 + wm + i * 16 + ko * 4 + r;
                float v = acc[i][j][r];
                if constexpr (EPI == EPI_QKV) {
                    int which = n >> 10, nn = n & 1023;
                    const float* bp = (which == 0) ? b0 : (which == 1 ? b1 : b2);
                    v += bp[nn];
                    float vp = __shfl_xor(v, 1);          // RoPE partner (col^1), all lanes
                    int bi = m >> 11, t = m & 2047, hh = nn >> 6, d = nn & 63;
                    size_t oidx = ((size_t)((bi * NHEAD + hh) * T_SEQ + t)) * DHEAD + d;
                    u16* outp = (u16*)outv + (size_t)which * HBUF;
                    if (which < 2) {
                        size_t ci = ((size_t)((bi * NHEAD + hh) * T_SEQ + t)) * 32 + (d >> 1);
                        float c = cosp[ci], sn = sinp[ci];
                        float o = (d & 1) ? (vp * sn + v * c) : (v * c - vp * sn);
                        if (which == 0) o *= 0.125f;      // 1/sqrt(DH) folded into Q
                        outp[oidx] = f2bf(o);
                    } else {
                        outp[oidx] = f2bf(v);
                    }
                } else if constexpr (EPI == EPI_RESF) {
                    v += b0[n] + resid[(size_t)m * N + n];
                    ((float*)outv)[(size_t)m * N + n] = v;   // f32 residual stream
                } else if constexpr (EPI == EPI_GELU) {
                    v += b0[n];
                    float gl = 0.5f * v * (1.f + erff(v * 0.70710678118654752f));
                    ((u16*)outv)[(size_t)m * N + n] = f2bf(gl);
                } else { // EPI_RES2 -> f32 final output
                    v += b0[n] + resid[(size_t)m * N + n];
                    ((float*)outv)[(size_t)m * N + n] = v;
                }
            }
        }
    }
}

// ---------------- causal attention: one block per (bh, q) row ----------------
__global__ __launch_bounds__(256) void attn_k(const u16* __restrict__ Q,
                                              const u16* __restrict__ K,
                                              const u16* __restrict__ V,
                                              u16* __restrict__ out)
{
    __shared__ float sS[T_SEQ];
    __shared__ float qf[DHEAD];
    __shared__ float red[4];
    __shared__ float pvred[4][DHEAD];
    int q = blockIdx.x, bh = blockIdx.y, tid = threadIdx.x;
    const u16* Qp = Q + ((size_t)bh * T_SEQ + q) * DHEAD;
    const u16* Kp = K + (size_t)bh * T_SEQ * DHEAD;
    const u16* Vp = V + (size_t)bh * T_SEQ * DHEAD;
    if (tid < DHEAD) qf[tid] = bf2f(Qp[tid]);   // Q already scaled by 1/8
    __syncthreads();
    int nk = q + 1;

    float lmax = -3.4e38f;
    for (int k = tid; k < nk; k += 256) {
        const u16* kr = Kp + (size_t)k * DHEAD;
        float dot = 0.f;
        #pragma unroll
        for (int c = 0; c < 8; c++) {
            u16x8 kv = *(const u16x8*)(kr + c * 8);
            #pragma unroll
            for (int e = 0; e < 8; e++) dot += qf[c * 8 + e] * bf2f(kv[e]);
        }
        sS[k] = dot;
        lmax = fmaxf(lmax, dot);
    }
    #pragma unroll
    for (int o = 32; o; o >>= 1) lmax = fmaxf(lmax, __shfl_xor(lmax, o));
    if ((tid & 63) == 0) red[tid >> 6] = lmax;
    __syncthreads();
    float bmax = fmaxf(fmaxf(red[0], red[1]), fmaxf(red[2], red[3]));

    float lsum = 0.f;
    for (int k = tid; k < nk; k += 256) {
        float p = __expf(sS[k] - bmax);
        sS[k] = p;
        lsum += p;
    }
    #pragma unroll
    for (int o = 32; o; o >>= 1) lsum += __shfl_xor(lsum, o);
    __syncthreads();                       // done reading red (bmax) everywhere
    if ((tid & 63) == 0) red[tid >> 6] = lsum;
    __syncthreads();
    float inv = 1.f / (red[0] + red[1] + red[2] + red[3]);

    int d = tid & 63, part = tid >> 6;
    float acc = 0.f;
    for (int k = part; k < nk; k += 4)
        acc += sS[k] * bf2f(Vp[(size_t)k * DHEAD + d]);
    pvred[part][d] = acc;
    __syncthreads();
    if (tid < DHEAD) {
        float o = (pvred[0][tid] + pvred[1][tid] + pvred[2][tid] + pvred[3][tid]) * inv;
        int bi = bh >> 4, hh = bh & 15;
        out[((size_t)(bi * T_SEQ + q)) * DMODEL + hh * DHEAD + tid] = f2bf(o);
    }
}

// ---------------- host launch ----------------
extern "C" void kernel_launch(void* const* d_in, const int* in_sizes, int n_in,
                              void* d_out, int out_size, void* d_ws, size_t ws_size,
                              hipStream_t stream)
{
    (void)in_sizes; (void)n_in; (void)out_size; (void)ws_size;
    const float* x    = (const float*)d_in[0];
    const float* cosp = (const float*)d_in[1];
    const float* sinp = (const float*)d_in[2];
    // d_in[3] causal_mask: unused (recomputed from indices)
    const float* Wq  = (const float*)d_in[4];
    const float* bq  = (const float*)d_in[5];
    const float* Wk  = (const float*)d_in[6];
    const float* bk  = (const float*)d_in[7];
    const float* Wv  = (const float*)d_in[8];
    const float* bv  = (const float*)d_in[9];
    const float* Wo  = (const float*)d_in[10];
    const float* bo  = (const float*)d_in[11];
    const float* g1  = (const float*)d_in[12];
    const float* b1n = (const float*)d_in[13];
    const float* g2  = (const float*)d_in[14];
    const float* b2n = (const float*)d_in[15];
    const float* W1  = (const float*)d_in[16];
    const float* bf1 = (const float*)d_in[17];
    const float* W2  = (const float*)d_in[18];
    const float* bf2 = (const float*)d_in[19];

    char* ws = (char*)d_ws;
    const size_t MB = 1024 * 1024;
    u16*   qkvT  = (u16*)(ws + 0);        // Wq^T,Wk^T,Wv^T bf16 contiguous: (3072,1024), 6 MB
    u16*   WoT   = (u16*)(ws + 6 * MB);   // 2 MB
    u16*   W1T   = (u16*)(ws + 8 * MB);   // (4096,1024), 8 MB
    u16*   W2T   = (u16*)(ws + 16 * MB);  // (1024,4096), 8 MB
    u16*   h     = (u16*)(ws + 24 * MB);  // LN output bf16 (reused as h2), 8 MB
    u16*   qkvh  = (u16*)(ws + 32 * MB);  // Q,K,V bf16 in (B,H,T,DH), 3x8 MB
    u16*   attnC = (u16*)(ws + 56 * MB);  // attention out bf16 (B,T,D), 8 MB
    float* x2    = (float*)(ws + 64 * MB);// f32 residual stream, 16 MB
    u16*   ffnh  = (u16*)(ws + 80 * MB);  // bf16 (4096,4096), 32 MB   -> total 112 MB

    // weight transposes + bf16 convert (B^T layout for the GEMMs)
    tr_k<<<dim3(16, 16), 256, 0, stream>>>(Wq, qkvT,               1024, 1024);
    tr_k<<<dim3(16, 16), 256, 0, stream>>>(Wk, qkvT + 1 * MB,      1024, 1024);
    tr_k<<<dim3(16, 16), 256, 0, stream>>>(Wv, qkvT + 2 * MB,      1024, 1024);
    tr_k<<<dim3(16, 16), 256, 0, stream>>>(Wo, WoT,                1024, 1024);
    tr_k<<<dim3(64, 16), 256, 0, stream>>>(W1, W1T,                1024, 4096);
    tr_k<<<dim3(16, 64), 256, 0, stream>>>(W2, W2T,                4096, 1024);

    ln_k<<<4096, 256, 0, stream>>>(x, g1, b1n, h);
    gemm_k<EPI_QKV><<<dim3(24, 32), 256, 0, stream>>>(
        h, qkvT, qkvh, 4096, 3072, 1024, bq, bk, bv, nullptr, cosp, sinp);
    attn_k<<<dim3(T_SEQ, 32), 256, 0, stream>>>(qkvh, qkvh + HBUF, qkvh + 2 * HBUF, attnC);
    gemm_k<EPI_RESF><<<dim3(8, 32), 256, 0, stream>>>(
        attnC, WoT, x2, 4096, 1024, 1024, bo, nullptr, nullptr, x, nullptr, nullptr);
    ln_k<<<4096, 256, 0, stream>>>(x2, g2, b2n, h);
    gemm_k<EPI_GELU><<<dim3(32, 32), 256, 0, stream>>>(
        h, W1T, ffnh, 4096, 4096, 1024, bf1, nullptr, nullptr, nullptr, nullptr, nullptr);
    gemm_k<EPI_RES2><<<dim3(8, 32), 256, 0, stream>>>(
        ffnh, W2T, (float*)d_out, 4096, 1024, 4096, bf2, nullptr, nullptr, x2, nullptr, nullptr);
}

// Round 3
// 547.432 us; speedup vs baseline: 5.0854x; 5.0854x over previous
//
#include <hip/hip_runtime.h>

typedef unsigned short u16;
typedef unsigned int   u32;
typedef __attribute__((ext_vector_type(8))) short          short8;
typedef __attribute__((ext_vector_type(4))) float          f32x4;
typedef __attribute__((ext_vector_type(8))) unsigned short u16x8;
typedef __attribute__((ext_vector_type(4))) unsigned short u16x4;

#define T_SEQ  2048
#define DMODEL 1024
#define NHEAD  16
#define DHEAD  64
#define HBUF   4194304   // elems in one (B,H,T,DH) buffer = 2*16*2048*64

__device__ __forceinline__ float bf2f(u16 u) {
    u32 i = ((u32)u) << 16; float f; __builtin_memcpy(&f, &i, 4); return f;
}
__device__ __forceinline__ u16 f2bf(float f) {
    u32 x; __builtin_memcpy(&x, &f, 4);
    return (u16)((x + 0x7FFFu + ((x >> 16) & 1u)) >> 16);   // RNE
}

// ---------------- LayerNorm (f32 in -> bf16 out): one block per row of 1024 ----------------
__global__ __launch_bounds__(256) void ln_k(const float* __restrict__ x,
                                            const float* __restrict__ g,
                                            const float* __restrict__ bb,
                                            u16* __restrict__ out)
{
    int row = blockIdx.x, tid = threadIdx.x;
    const float* xr = x + (size_t)row * DMODEL;
    f32x4 v = *(const f32x4*)(xr + tid * 4);
    float s  = v[0] + v[1] + v[2] + v[3];
    float s2 = v[0]*v[0] + v[1]*v[1] + v[2]*v[2] + v[3]*v[3];
    #pragma unroll
    for (int o = 32; o; o >>= 1) { s += __shfl_xor(s, o); s2 += __shfl_xor(s2, o); }
    __shared__ float rs[4], rq[4];
    if ((tid & 63) == 0) { rs[tid >> 6] = s; rq[tid >> 6] = s2; }
    __syncthreads();
    float S  = rs[0] + rs[1] + rs[2] + rs[3];
    float S2 = rq[0] + rq[1] + rq[2] + rq[3];
    float mean = S * (1.f / DMODEL);
    float var  = S2 * (1.f / DMODEL) - mean * mean;
    float rstd = rsqrtf(var + 1e-5f);
    f32x4 gv = *(const f32x4*)(g + tid * 4);
    f32x4 bv = *(const f32x4*)(bb + tid * 4);
    u16x4 o;
    #pragma unroll
    for (int e = 0; e < 4; e++)
        o[e] = f2bf((v[e] - mean) * rstd * gv[e] + bv[e]);
    *(u16x4*)(out + (size_t)row * DMODEL + tid * 4) = o;
}

// -------- 64x64-tile transpose + f32->bf16 convert: out[c][r] = bf16(in[r][c]) --------
__global__ __launch_bounds__(256) void tr_k(const float* __restrict__ in,
                                            u16* __restrict__ out, int R, int C)
{
    __shared__ u16 s[64][72];
    int tid = threadIdx.x;
    int c0 = blockIdx.x * 64, r0 = blockIdx.y * 64;
    #pragma unroll
    for (int p = 0; p < 2; p++) {
        int r = (tid >> 3) + p * 32, cq = (tid & 7) * 8;
        const float* ip = in + (size_t)(r0 + r) * C + c0 + cq;
        f32x4 a = *(const f32x4*)ip;
        f32x4 b = *(const f32x4*)(ip + 4);
        u16x8 o;
        #pragma unroll
        for (int e = 0; e < 4; e++) { o[e] = f2bf(a[e]); o[4 + e] = f2bf(b[e]); }
        *(u16x8*)(&s[r][cq]) = o;
    }
    __syncthreads();
    int oc = tid >> 2, kq = (tid & 3) * 16;
    u16 tmp[16] __attribute__((aligned(16)));
    #pragma unroll
    for (int e = 0; e < 16; e++) tmp[e] = s[kq + e][oc];
    u16* op = out + (size_t)(c0 + oc) * R + r0 + kq;
    *(u16x8*)op       = *(const u16x8*)(&tmp[0]);
    *(u16x8*)(op + 8) = *(const u16x8*)(&tmp[8]);
}

// ---------------- MFMA GEMM: C = A[M,K] @ Bt[N,K]^T (bf16 in, f32 acc), fused epilogues ----------------
constexpr int EPI_QKV = 0, EPI_RESF = 1, EPI_GELU = 2, EPI_RES2 = 3;

template<int EPI>
__global__ __launch_bounds__(256) void gemm_k(
    const u16* __restrict__ A, const u16* __restrict__ Bt, void* __restrict__ outv,
    int M, int N, int K,
    const float* __restrict__ b0, const float* __restrict__ b1, const float* __restrict__ b2,
    const float* __restrict__ resid,
    const float* __restrict__ cosp, const float* __restrict__ sinp)
{
    __shared__ u16 As[128 * 40];
    __shared__ u16 Bs[128 * 40];
    int tid = threadIdx.x;
    int n0 = blockIdx.x * 128, m0 = blockIdx.y * 128;
    int wave = tid >> 6, lane = tid & 63, lm = lane & 15, ko = lane >> 4;
    int wm = (wave & 1) * 64, wn = (wave >> 1) * 64;
    f32x4 acc[4][4];
    #pragma unroll
    for (int i = 0; i < 4; i++)
        #pragma unroll
        for (int j = 0; j < 4; j++) acc[i][j] = (f32x4){0.f, 0.f, 0.f, 0.f};

    int sr = tid >> 2, sq = tid & 3;
    const u16* Ab = A  + (size_t)m0 * K;
    const u16* Bb = Bt + (size_t)n0 * K;

    for (int kt = 0; kt < K; kt += 32) {
        __syncthreads();
        #pragma unroll
        for (int p = 0; p < 2; p++) {
            int r = sr + p * 64;
            *(u16x8*)(&As[r * 40 + sq * 8]) = *(const u16x8*)(Ab + (size_t)r * K + kt + sq * 8);
            *(u16x8*)(&Bs[r * 40 + sq * 8]) = *(const u16x8*)(Bb + (size_t)r * K + kt + sq * 8);
        }
        __syncthreads();
        short8 af[4], bf[4];
        #pragma unroll
        for (int i = 0; i < 4; i++) af[i] = *(const short8*)(&As[(wm + i * 16 + lm) * 40 + ko * 8]);
        #pragma unroll
        for (int j = 0; j < 4; j++) bf[j] = *(const short8*)(&Bs[(wn + j * 16 + lm) * 40 + ko * 8]);
        #pragma unroll
        for (int i = 0; i < 4; i++)
            #pragma unroll
            for (int j = 0; j < 4; j++)
                acc[i][j] = __builtin_amdgcn_mfma_f32_16x16x32_bf16(af[i], bf[j], acc[i][j], 0, 0, 0);
    }

    // epilogue — C/D layout: col = lane&15, row = (lane>>4)*4 + reg  [m89/m91]
    #pragma unroll
    for (int i = 0; i < 4; i++) {
        #pragma unroll
        for (int j = 0; j < 4; j++) {
            int n = n0 + wn + j * 16 + lm;
            #pragma unroll
            for (int r = 0; r < 4; r++) {
                int m = m0 + wm + i * 16 + ko * 4 + r;
                float v = acc[i][j][r];
                if constexpr (EPI == EPI_QKV) {
                    int which = n >> 10, nn = n & 1023;
                    const float* bp = (which == 0) ? b0 : (which == 1 ? b1 : b2);
                    v += bp[nn];
                    float vp = __shfl_xor(v, 1);          // RoPE partner (col^1), all lanes
                    int bi = m >> 11, t = m & 2047, hh = nn >> 6, d = nn & 63;
                    u16* outp = (u16*)outv + (size_t)which * HBUF;
                    if (which < 2) {
                        size_t oidx = ((size_t)((bi * NHEAD + hh) * T_SEQ + t)) * DHEAD + d;
                        size_t ci = ((size_t)((bi * NHEAD + hh) * T_SEQ + t)) * 32 + (d >> 1);
                        float c = cosp[ci], sn = sinp[ci];
                        float o = (d & 1) ? (vp * sn + v * c) : (v * c - vp * sn);
                        if (which == 0) o *= 0.125f;      // 1/sqrt(DH) folded into Q
                        outp[oidx] = f2bf(o);
                    } else {
                        // V stored TRANSPOSED per head: (B,H,DH,T) for flash-attn B-frags
                        size_t oidx = ((size_t)((bi * NHEAD + hh) * DHEAD + d)) * T_SEQ + t;
                        outp[oidx] = f2bf(v);
                    }
                } else if constexpr (EPI == EPI_RESF) {
                    v += b0[n] + resid[(size_t)m * N + n];
                    ((float*)outv)[(size_t)m * N + n] = v;   // f32 residual stream
                } else if constexpr (EPI == EPI_GELU) {
                    v += b0[n];
                    float gl = 0.5f * v * (1.f + erff(v * 0.70710678118654752f));
                    ((u16*)outv)[(size_t)m * N + n] = f2bf(gl);
                } else { // EPI_RES2 -> f32 final output
                    v += b0[n] + resid[(size_t)m * N + n];
                    ((float*)outv)[(size_t)m * N + n] = v;
                }
            }
        }
    }
}

// ---------------- flash attention (MFMA): one block per (q-tile of 64, bh) ----------------
// Q: (B,H,T,DH) bf16 (pre-scaled by 1/8); K: (B,H,T,DH); Vt: (B,H,DH,T); out: (B,T,D)
__global__ __launch_bounds__(256) void fattn_k(const u16* __restrict__ Q,
                                               const u16* __restrict__ K,
                                               const u16* __restrict__ Vt,
                                               u16* __restrict__ out)
{
    __shared__ u16 sQ[64][72];
    __shared__ u16 sK[64][72];
    __shared__ u16 sV[64][72];          // [d][kpos]
    __shared__ u16 sP[4][16][72];       // per-wave P tile [qrow][kpos]
    int tid = threadIdx.x;
    int qt = blockIdx.x, bh = blockIdx.y;
    int wave = tid >> 6, lane = tid & 63, lm = lane & 15, ko = lane >> 4;
    int bi = bh >> 4, hh = bh & 15;

    const u16* Qb = Q  + ((size_t)bh * T_SEQ + qt * 64) * DHEAD;
    const u16* Kb = K  + (size_t)bh * T_SEQ * DHEAD;
    const u16* Vb = Vt + (size_t)bh * DHEAD * T_SEQ;

    int srow = tid >> 2, scol = (tid & 3) * 16;
    {
        const u16* gp = Qb + (size_t)srow * DHEAD + scol;
        *(u16x8*)(&sQ[srow][scol])     = *(const u16x8*)gp;
        *(u16x8*)(&sQ[srow][scol + 8]) = *(const u16x8*)(gp + 8);
    }
    __syncthreads();
    short8 aq0 = *(const short8*)(&sQ[wave * 16 + lm][ko * 8]);
    short8 aq1 = *(const short8*)(&sQ[wave * 16 + lm][32 + ko * 8]);

    f32x4 oacc[4];
    #pragma unroll
    for (int j = 0; j < 4; j++) oacc[j] = (f32x4){0.f, 0.f, 0.f, 0.f};
    float mr[4], lr[4];
    #pragma unroll
    for (int r = 0; r < 4; r++) { mr[r] = -1e30f; lr[r] = 0.f; }

    for (int kt = 0; kt <= qt; kt++) {
        __syncthreads();                         // prev iter done reading sK/sV
        {
            const u16* kp = Kb + ((size_t)(kt * 64 + srow)) * DHEAD + scol;
            *(u16x8*)(&sK[srow][scol])     = *(const u16x8*)kp;
            *(u16x8*)(&sK[srow][scol + 8]) = *(const u16x8*)(kp + 8);
            const u16* vp = Vb + (size_t)srow * T_SEQ + kt * 64 + scol;
            *(u16x8*)(&sV[srow][scol])     = *(const u16x8*)vp;
            *(u16x8*)(&sV[srow][scol + 8]) = *(const u16x8*)(vp + 8);
        }
        __syncthreads();

        // S = Q K^T for this wave's 16 rows x 64 cols
        f32x4 sacc[4];
        #pragma unroll
        for (int j = 0; j < 4; j++) {
            short8 bk0 = *(const short8*)(&sK[j * 16 + lm][ko * 8]);
            short8 bk1 = *(const short8*)(&sK[j * 16 + lm][32 + ko * 8]);
            f32x4 z = (f32x4){0.f, 0.f, 0.f, 0.f};
            z = __builtin_amdgcn_mfma_f32_16x16x32_bf16(aq0, bk0, z, 0, 0, 0);
            z = __builtin_amdgcn_mfma_f32_16x16x32_bf16(aq1, bk1, z, 0, 0, 0);
            sacc[j] = z;
        }
        if (kt == qt) {  // causal mask on diagonal tile: col > row -> -inf
            #pragma unroll
            for (int j = 0; j < 4; j++)
                #pragma unroll
                for (int r = 0; r < 4; r++)
                    if (j * 16 + lm > wave * 16 + ko * 4 + r) sacc[j][r] = -1e30f;
        }

        // online softmax update (rows = ko*4+r, replicated across 16-lane group)
        float vmax[4], rsum[4], alpha[4];
        #pragma unroll
        for (int r = 0; r < 4; r++)
            vmax[r] = fmaxf(fmaxf(sacc[0][r], sacc[1][r]), fmaxf(sacc[2][r], sacc[3][r]));
        #pragma unroll
        for (int o = 1; o < 16; o <<= 1)
            #pragma unroll
            for (int r = 0; r < 4; r++) vmax[r] = fmaxf(vmax[r], __shfl_xor(vmax[r], o));
        #pragma unroll
        for (int r = 0; r < 4; r++) {
            float mn = fmaxf(mr[r], vmax[r]);
            alpha[r] = __expf(mr[r] - mn);
            mr[r] = mn;
            rsum[r] = 0.f;
        }
        u16 pb[4][4];
        #pragma unroll
        for (int j = 0; j < 4; j++)
            #pragma unroll
            for (int r = 0; r < 4; r++) {
                float p = __expf(sacc[j][r] - mr[r]);
                rsum[r] += p;
                pb[j][r] = f2bf(p);
            }
        #pragma unroll
        for (int o = 1; o < 16; o <<= 1)
            #pragma unroll
            for (int r = 0; r < 4; r++) rsum[r] += __shfl_xor(rsum[r], o);
        #pragma unroll
        for (int r = 0; r < 4; r++) lr[r] = lr[r] * alpha[r] + rsum[r];
        #pragma unroll
        for (int j = 0; j < 4; j++)
            #pragma unroll
            for (int r = 0; r < 4; r++) oacc[j][r] *= alpha[r];

        // P -> LDS (C/D layout -> A-operand layout round trip)
        #pragma unroll
        for (int j = 0; j < 4; j++)
            #pragma unroll
            for (int r = 0; r < 4; r++) sP[wave][ko * 4 + r][j * 16 + lm] = pb[j][r];
        __syncthreads();

        // O += P V  (B-frag rows are sV[d][kpos] — contiguous)
        #pragma unroll
        for (int ks = 0; ks < 2; ks++) {
            short8 ap = *(const short8*)(&sP[wave][lm][ks * 32 + ko * 8]);
            #pragma unroll
            for (int j = 0; j < 4; j++) {
                short8 bv = *(const short8*)(&sV[j * 16 + lm][ks * 32 + ko * 8]);
                oacc[j] = __builtin_amdgcn_mfma_f32_16x16x32_bf16(ap, bv, oacc[j], 0, 0, 0);
            }
        }
    }

    float inv[4];
    #pragma unroll
    for (int r = 0; r < 4; r++) inv[r] = 1.f / lr[r];
    int qrow = qt * 64 + wave * 16;
    #pragma unroll
    for (int j = 0; j < 4; j++)
        #pragma unroll
        for (int r = 0; r < 4; r++)
            out[((size_t)(bi * T_SEQ) + qrow + ko * 4 + r) * DMODEL + hh * DHEAD + j * 16 + lm]
                = f2bf(oacc[j][r] * inv[r]);
}

// ---------------- host launch ----------------
extern "C" void kernel_launch(void* const* d_in, const int* in_sizes, int n_in,
                              void* d_out, int out_size, void* d_ws, size_t ws_size,
                              hipStream_t stream)
{
    (void)in_sizes; (void)n_in; (void)out_size; (void)ws_size;
    const float* x    = (const float*)d_in[0];
    const float* cosp = (const float*)d_in[1];
    const float* sinp = (const float*)d_in[2];
    // d_in[3] causal_mask: unused (recomputed from indices)
    const float* Wq  = (const float*)d_in[4];
    const float* bq  = (const float*)d_in[5];
    const float* Wk  = (const float*)d_in[6];
    const float* bk  = (const float*)d_in[7];
    const float* Wv  = (const float*)d_in[8];
    const float* bv  = (const float*)d_in[9];
    const float* Wo  = (const float*)d_in[10];
    const float* bo  = (const float*)d_in[11];
    const float* g1  = (const float*)d_in[12];
    const float* b1n = (const float*)d_in[13];
    const float* g2  = (const float*)d_in[14];
    const float* b2n = (const float*)d_in[15];
    const float* W1  = (const float*)d_in[16];
    const float* bf1 = (const float*)d_in[17];
    const float* W2  = (const float*)d_in[18];
    const float* bf2 = (const float*)d_in[19];

    char* ws = (char*)d_ws;
    const size_t MB = 1024 * 1024;
    u16*   qkvT  = (u16*)(ws + 0);        // Wq^T,Wk^T,Wv^T bf16 contiguous: (3072,1024), 6 MB
    u16*   WoT   = (u16*)(ws + 6 * MB);   // 2 MB
    u16*   W1T   = (u16*)(ws + 8 * MB);   // (4096,1024), 8 MB
    u16*   W2T   = (u16*)(ws + 16 * MB);  // (1024,4096), 8 MB
    u16*   h     = (u16*)(ws + 24 * MB);  // LN output bf16 (reused as h2), 8 MB
    u16*   qkvh  = (u16*)(ws + 32 * MB);  // Q,K in (B,H,T,DH); V in (B,H,DH,T), 3x8 MB
    u16*   attnC = (u16*)(ws + 56 * MB);  // attention out bf16 (B,T,D), 8 MB
    float* x2    = (float*)(ws + 64 * MB);// f32 residual stream, 16 MB
    u16*   ffnh  = (u16*)(ws + 80 * MB);  // bf16 (4096,4096), 32 MB   -> total 112 MB

    // weight transposes + bf16 convert (B^T layout for the GEMMs)
    tr_k<<<dim3(16, 16), 256, 0, stream>>>(Wq, qkvT,               1024, 1024);
    tr_k<<<dim3(16, 16), 256, 0, stream>>>(Wk, qkvT + 1 * MB,      1024, 1024);
    tr_k<<<dim3(16, 16), 256, 0, stream>>>(Wv, qkvT + 2 * MB,      1024, 1024);
    tr_k<<<dim3(16, 16), 256, 0, stream>>>(Wo, WoT,                1024, 1024);
    tr_k<<<dim3(64, 16), 256, 0, stream>>>(W1, W1T,                1024, 4096);
    tr_k<<<dim3(16, 64), 256, 0, stream>>>(W2, W2T,                4096, 1024);

    ln_k<<<4096, 256, 0, stream>>>(x, g1, b1n, h);
    gemm_k<EPI_QKV><<<dim3(24, 32), 256, 0, stream>>>(
        h, qkvT, qkvh, 4096, 3072, 1024, bq, bk, bv, nullptr, cosp, sinp);
    fattn_k<<<dim3(32, 32), 256, 0, stream>>>(qkvh, qkvh + HBUF, qkvh + 2 * HBUF, attnC);
    gemm_k<EPI_RESF><<<dim3(8, 32), 256, 0, stream>>>(
        attnC, WoT, x2, 4096, 1024, 1024, bo, nullptr, nullptr, x, nullptr, nullptr);
    ln_k<<<4096, 256, 0, stream>>>(x2, g2, b2n, h);
    gemm_k<EPI_GELU><<<dim3(32, 32), 256, 0, stream>>>(
        h, W1T, ffnh, 4096, 4096, 1024, bf1, nullptr, nullptr, nullptr, nullptr, nullptr);
    gemm_k<EPI_RES2><<<dim3(8, 32), 256, 0, stream>>>(
        ffnh, W2T, (float*)d_out, 4096, 1024, 4096, bf2, nullptr, nullptr, x2, nullptr, nullptr);
}

// Round 4
// 541.610 us; speedup vs baseline: 5.1400x; 1.0107x over previous
//
#include <hip/hip_runtime.h>

typedef unsigned short u16;
typedef unsigned int   u32;
typedef __attribute__((ext_vector_type(8))) short          short8;
typedef __attribute__((ext_vector_type(4))) float          f32x4;
typedef __attribute__((ext_vector_type(8))) unsigned short u16x8;
typedef __attribute__((ext_vector_type(4))) unsigned short u16x4;

#define T_SEQ  2048
#define DMODEL 1024
#define NHEAD  16
#define DHEAD  64
#define HBUF   4194304   // elems in one (B,H,T,DH) buffer = 2*16*2048*64

__device__ __forceinline__ float bf2f(u16 u) {
    u32 i = ((u32)u) << 16; float f; __builtin_memcpy(&f, &i, 4); return f;
}
__device__ __forceinline__ u16 f2bf(float f) {
    u32 x; __builtin_memcpy(&x, &f, 4);
    return (u16)((x + 0x7FFFu + ((x >> 16) & 1u)) >> 16);   // RNE
}

// async global->LDS, 16B per lane; LDS dest = wave-uniform base + lane*16 (m97/m104)
__device__ __forceinline__ void gld16(const u16* g, u16* l) {
    auto gp = reinterpret_cast<const __attribute__((address_space(1))) u32*>(
        reinterpret_cast<uintptr_t>(g));
    auto lp = reinterpret_cast<__attribute__((address_space(3))) u32*>(
        (u32)reinterpret_cast<uintptr_t>(l));
    __builtin_amdgcn_global_load_lds(gp, lp, 16, 0, 0);
}

// ---------------- LayerNorm (f32 in -> bf16 out): one block per row of 1024 ----------------
__global__ __launch_bounds__(256) void ln_k(const float* __restrict__ x,
                                            const float* __restrict__ g,
                                            const float* __restrict__ bb,
                                            u16* __restrict__ out)
{
    int row = blockIdx.x, tid = threadIdx.x;
    const float* xr = x + (size_t)row * DMODEL;
    f32x4 v = *(const f32x4*)(xr + tid * 4);
    float s  = v[0] + v[1] + v[2] + v[3];
    float s2 = v[0]*v[0] + v[1]*v[1] + v[2]*v[2] + v[3]*v[3];
    #pragma unroll
    for (int o = 32; o; o >>= 1) { s += __shfl_xor(s, o); s2 += __shfl_xor(s2, o); }
    __shared__ float rs[4], rq[4];
    if ((tid & 63) == 0) { rs[tid >> 6] = s; rq[tid >> 6] = s2; }
    __syncthreads();
    float S  = rs[0] + rs[1] + rs[2] + rs[3];
    float S2 = rq[0] + rq[1] + rq[2] + rq[3];
    float mean = S * (1.f / DMODEL);
    float var  = S2 * (1.f / DMODEL) - mean * mean;
    float rstd = rsqrtf(var + 1e-5f);
    f32x4 gv = *(const f32x4*)(g + tid * 4);
    f32x4 bv = *(const f32x4*)(bb + tid * 4);
    u16x4 o;
    #pragma unroll
    for (int e = 0; e < 4; e++)
        o[e] = f2bf((v[e] - mean) * rstd * gv[e] + bv[e]);
    *(u16x4*)(out + (size_t)row * DMODEL + tid * 4) = o;
}

// -------- 64x64-tile transpose + f32->bf16 convert: out[c][r] = bf16(in[r][c]) --------
__global__ __launch_bounds__(256) void tr_k(const float* __restrict__ in,
                                            u16* __restrict__ out, int R, int C)
{
    __shared__ u16 s[64][72];
    int tid = threadIdx.x;
    int c0 = blockIdx.x * 64, r0 = blockIdx.y * 64;
    #pragma unroll
    for (int p = 0; p < 2; p++) {
        int r = (tid >> 3) + p * 32, cq = (tid & 7) * 8;
        const float* ip = in + (size_t)(r0 + r) * C + c0 + cq;
        f32x4 a = *(const f32x4*)ip;
        f32x4 b = *(const f32x4*)(ip + 4);
        u16x8 o;
        #pragma unroll
        for (int e = 0; e < 4; e++) { o[e] = f2bf(a[e]); o[4 + e] = f2bf(b[e]); }
        *(u16x8*)(&s[r][cq]) = o;
    }
    __syncthreads();
    int oc = tid >> 2, kq = (tid & 3) * 16;
    u16 tmp[16] __attribute__((aligned(16)));
    #pragma unroll
    for (int e = 0; e < 16; e++) tmp[e] = s[kq + e][oc];
    u16* op = out + (size_t)(c0 + oc) * R + r0 + kq;
    *(u16x8*)op       = *(const u16x8*)(&tmp[0]);
    *(u16x8*)(op + 8) = *(const u16x8*)(&tmp[8]);
}

// ---------------- MFMA GEMM: C = A[M,K] @ Bt[N,K]^T (bf16 in, f32 acc), fused epilogues ----------------
// m97 pattern: global_load_lds width=16 into UNPADDED [128][32] LDS tiles.
constexpr int EPI_QKV = 0, EPI_RESF = 1, EPI_GELU = 2, EPI_RES2 = 3;

template<int EPI>
__global__ __launch_bounds__(256) void gemm_k(
    const u16* __restrict__ A, const u16* __restrict__ Bt, void* __restrict__ outv,
    int M, int N, int K,
    const float* __restrict__ b0, const float* __restrict__ b1, const float* __restrict__ b2,
    const float* __restrict__ resid,
    const float* __restrict__ cosp, const float* __restrict__ sinp)
{
    __shared__ u16 As[128 * 32];
    __shared__ u16 Bs[128 * 32];
    int tid = threadIdx.x;
    int n0 = blockIdx.x * 128, m0 = blockIdx.y * 128;
    int wave = tid >> 6, lane = tid & 63, lm = lane & 15, ko = lane >> 4;
    int wm = (wave & 1) * 64, wn = (wave >> 1) * 64;
    f32x4 acc[4][4];
    #pragma unroll
    for (int i = 0; i < 4; i++)
        #pragma unroll
        for (int j = 0; j < 4; j++) acc[i][j] = (f32x4){0.f, 0.f, 0.f, 0.f};

    // staging coords: instr p covers tile rows p*64 + wave*16 + (lane>>2), u16 col (lane&3)*8
    int srow = wave * 16 + (lane >> 2);
    int scol = (lane & 3) * 8;
    const u16* Ag = A  + (size_t)(m0 + srow) * K + scol;
    const u16* Bg = Bt + (size_t)(n0 + srow) * K + scol;
    u16* Al = &As[wave * 16 * 32];    // wave-uniform LDS bases
    u16* Bl = &Bs[wave * 16 * 32];

    for (int kt = 0; kt < K; kt += 32) {
        __syncthreads();
        gld16(Ag,               Al);
        gld16(Ag + 64 * (size_t)K, Al + 64 * 32);
        gld16(Bg,               Bl);
        gld16(Bg + 64 * (size_t)K, Bl + 64 * 32);
        Ag += 32; Bg += 32;
        __syncthreads();            // compiler drains vmcnt(0) before s_barrier
        short8 af[4], bf[4];
        #pragma unroll
        for (int i = 0; i < 4; i++) af[i] = *(const short8*)(&As[(wm + i * 16 + lm) * 32 + ko * 8]);
        #pragma unroll
        for (int j = 0; j < 4; j++) bf[j] = *(const short8*)(&Bs[(wn + j * 16 + lm) * 32 + ko * 8]);
        #pragma unroll
        for (int i = 0; i < 4; i++)
            #pragma unroll
            for (int j = 0; j < 4; j++)
                acc[i][j] = __builtin_amdgcn_mfma_f32_16x16x32_bf16(af[i], bf[j], acc[i][j], 0, 0, 0);
    }

    // epilogue — C/D layout: col = lane&15, row = (lane>>4)*4 + reg  [m89/m91]
    #pragma unroll
    for (int i = 0; i < 4; i++) {
        #pragma unroll
        for (int j = 0; j < 4; j++) {
            int n = n0 + wn + j * 16 + lm;
            #pragma unroll
            for (int r = 0; r < 4; r++) {
                int m = m0 + wm + i * 16 + ko * 4 + r;
                float v = acc[i][j][r];
                if constexpr (EPI == EPI_QKV) {
                    int which = n >> 10, nn = n & 1023;
                    const float* bp = (which == 0) ? b0 : (which == 1 ? b1 : b2);
                    v += bp[nn];
                    float vp = __shfl_xor(v, 1);          // RoPE partner (col^1), all lanes
                    int bi = m >> 11, t = m & 2047, hh = nn >> 6, d = nn & 63;
                    u16* outp = (u16*)outv + (size_t)which * HBUF;
                    if (which < 2) {
                        size_t oidx = ((size_t)((bi * NHEAD + hh) * T_SEQ + t)) * DHEAD + d;
                        size_t ci = ((size_t)((bi * NHEAD + hh) * T_SEQ + t)) * 32 + (d >> 1);
                        float c = cosp[ci], sn = sinp[ci];
                        float o = (d & 1) ? (vp * sn + v * c) : (v * c - vp * sn);
                        if (which == 0) o *= 0.125f;      // 1/sqrt(DH) folded into Q
                        outp[oidx] = f2bf(o);
                    } else {
                        // V stored TRANSPOSED per head: (B,H,DH,T) for flash-attn B-frags
                        size_t oidx = ((size_t)((bi * NHEAD + hh) * DHEAD + d)) * T_SEQ + t;
                        outp[oidx] = f2bf(v);
                    }
                } else if constexpr (EPI == EPI_RESF) {
                    v += b0[n] + resid[(size_t)m * N + n];
                    ((float*)outv)[(size_t)m * N + n] = v;   // f32 residual stream
                } else if constexpr (EPI == EPI_GELU) {
                    v += b0[n];
                    float gl = 0.5f * v * (1.f + erff(v * 0.70710678118654752f));
                    ((u16*)outv)[(size_t)m * N + n] = f2bf(gl);
                } else { // EPI_RES2 -> f32 final output
                    v += b0[n] + resid[(size_t)m * N + n];
                    ((float*)outv)[(size_t)m * N + n] = v;
                }
            }
        }
    }
}

// ---------------- flash attention (MFMA): one block per (q-tile of 64, bh) ----------------
// Q: (B,H,T,DH) bf16 (pre-scaled by 1/8); K: (B,H,T,DH); Vt: (B,H,DH,T); out: (B,T,D)
__global__ __launch_bounds__(256) void fattn_k(const u16* __restrict__ Q,
                                               const u16* __restrict__ K,
                                               const u16* __restrict__ Vt,
                                               u16* __restrict__ out)
{
    __shared__ u16 sQP[4][16][72];      // Q tile (prologue) then per-wave P tile
    __shared__ u16 sK[64][72];
    __shared__ u16 sV[64][72];          // [d][kpos]
    int tid = threadIdx.x;
    int qt = (int)gridDim.x - 1 - (int)blockIdx.x;   // longest blocks dispatch FIRST
    int bh = blockIdx.y;
    int wave = tid >> 6, lane = tid & 63, lm = lane & 15, ko = lane >> 4;
    int bi = bh >> 4, hh = bh & 15;

    const u16* Qb = Q  + ((size_t)bh * T_SEQ + qt * 64) * DHEAD;
    const u16* Kb = K  + (size_t)bh * T_SEQ * DHEAD;
    const u16* Vb = Vt + (size_t)bh * DHEAD * T_SEQ;
    u16* sQf = &sQP[0][0][0];

    int srow = tid >> 2, scol = (tid & 3) * 16;
    {
        const u16* gp = Qb + (size_t)srow * DHEAD + scol;
        *(u16x8*)(&sQf[srow * 72 + scol])     = *(const u16x8*)gp;
        *(u16x8*)(&sQf[srow * 72 + scol + 8]) = *(const u16x8*)(gp + 8);
    }
    __syncthreads();
    short8 aq0 = *(const short8*)(&sQf[(wave * 16 + lm) * 72 + ko * 8]);
    short8 aq1 = *(const short8*)(&sQf[(wave * 16 + lm) * 72 + 32 + ko * 8]);
    // after this point sQP[wave] is wave-private scratch (P tile)

    f32x4 oacc[4];
    #pragma unroll
    for (int j = 0; j < 4; j++) oacc[j] = (f32x4){0.f, 0.f, 0.f, 0.f};
    float mr[4], lr[4];
    #pragma unroll
    for (int r = 0; r < 4; r++) { mr[r] = -1e30f; lr[r] = 0.f; }

    for (int kt = 0; kt <= qt; kt++) {
        __syncthreads();                         // prev iter done reading sK/sV
        {
            const u16* kp = Kb + ((size_t)(kt * 64 + srow)) * DHEAD + scol;
            *(u16x8*)(&sK[srow][scol])     = *(const u16x8*)kp;
            *(u16x8*)(&sK[srow][scol + 8]) = *(const u16x8*)(kp + 8);
            const u16* vp = Vb + (size_t)srow * T_SEQ + kt * 64 + scol;
            *(u16x8*)(&sV[srow][scol])     = *(const u16x8*)vp;
            *(u16x8*)(&sV[srow][scol + 8]) = *(const u16x8*)(vp + 8);
        }
        __syncthreads();

        // S = Q K^T for this wave's 16 rows x 64 cols
        f32x4 sacc[4];
        #pragma unroll
        for (int j = 0; j < 4; j++) {
            short8 bk0 = *(const short8*)(&sK[j * 16 + lm][ko * 8]);
            short8 bk1 = *(const short8*)(&sK[j * 16 + lm][32 + ko * 8]);
            f32x4 z = (f32x4){0.f, 0.f, 0.f, 0.f};
            z = __builtin_amdgcn_mfma_f32_16x16x32_bf16(aq0, bk0, z, 0, 0, 0);
            z = __builtin_amdgcn_mfma_f32_16x16x32_bf16(aq1, bk1, z, 0, 0, 0);
            sacc[j] = z;
        }
        if (kt == qt) {  // causal mask on diagonal tile: col > row -> -inf
            #pragma unroll
            for (int j = 0; j < 4; j++)
                #pragma unroll
                for (int r = 0; r < 4; r++)
                    if (j * 16 + lm > wave * 16 + ko * 4 + r) sacc[j][r] = -1e30f;
        }

        // online softmax update (rows = ko*4+r, replicated across 16-lane group)
        float vmax[4], rsum[4], alpha[4];
        #pragma unroll
        for (int r = 0; r < 4; r++)
            vmax[r] = fmaxf(fmaxf(sacc[0][r], sacc[1][r]), fmaxf(sacc[2][r], sacc[3][r]));
        #pragma unroll
        for (int o = 1; o < 16; o <<= 1)
            #pragma unroll
            for (int r = 0; r < 4; r++) vmax[r] = fmaxf(vmax[r], __shfl_xor(vmax[r], o));
        #pragma unroll
        for (int r = 0; r < 4; r++) {
            float mn = fmaxf(mr[r], vmax[r]);
            alpha[r] = __expf(mr[r] - mn);
            mr[r] = mn;
            rsum[r] = 0.f;
        }
        u16 pb[4][4];
        #pragma unroll
        for (int j = 0; j < 4; j++)
            #pragma unroll
            for (int r = 0; r < 4; r++) {
                float p = __expf(sacc[j][r] - mr[r]);
                rsum[r] += p;
                pb[j][r] = f2bf(p);
            }
        #pragma unroll
        for (int o = 1; o < 16; o <<= 1)
            #pragma unroll
            for (int r = 0; r < 4; r++) rsum[r] += __shfl_xor(rsum[r], o);
        #pragma unroll
        for (int r = 0; r < 4; r++) lr[r] = lr[r] * alpha[r] + rsum[r];
        #pragma unroll
        for (int j = 0; j < 4; j++)
            #pragma unroll
            for (int r = 0; r < 4; r++) oacc[j][r] *= alpha[r];

        // P -> LDS (C/D layout -> A-operand layout); sQP[wave] is wave-private,
        // in-wave LDS ops are in-order => NO barrier needed
        #pragma unroll
        for (int j = 0; j < 4; j++)
            #pragma unroll
            for (int r = 0; r < 4; r++) sQP[wave][ko * 4 + r][j * 16 + lm] = pb[j][r];

        // O += P V  (B-frag rows are sV[d][kpos] — contiguous)
        #pragma unroll
        for (int ks = 0; ks < 2; ks++) {
            short8 ap = *(const short8*)(&sQP[wave][lm][ks * 32 + ko * 8]);
            #pragma unroll
            for (int j = 0; j < 4; j++) {
                short8 bv = *(const short8*)(&sV[j * 16 + lm][ks * 32 + ko * 8]);
                oacc[j] = __builtin_amdgcn_mfma_f32_16x16x32_bf16(ap, bv, oacc[j], 0, 0, 0);
            }
        }
    }

    float inv[4];
    #pragma unroll
    for (int r = 0; r < 4; r++) inv[r] = 1.f / lr[r];
    int qrow = qt * 64 + wave * 16;
    #pragma unroll
    for (int j = 0; j < 4; j++)
        #pragma unroll
        for (int r = 0; r < 4; r++)
            out[((size_t)(bi * T_SEQ) + qrow + ko * 4 + r) * DMODEL + hh * DHEAD + j * 16 + lm]
                = f2bf(oacc[j][r] * inv[r]);
}

// ---------------- host launch ----------------
extern "C" void kernel_launch(void* const* d_in, const int* in_sizes, int n_in,
                              void* d_out, int out_size, void* d_ws, size_t ws_size,
                              hipStream_t stream)
{
    (void)in_sizes; (void)n_in; (void)out_size; (void)ws_size;
    const float* x    = (const float*)d_in[0];
    const float* cosp = (const float*)d_in[1];
    const float* sinp = (const float*)d_in[2];
    // d_in[3] causal_mask: unused (recomputed from indices)
    const float* Wq  = (const float*)d_in[4];
    const float* bq  = (const float*)d_in[5];
    const float* Wk  = (const float*)d_in[6];
    const float* bk  = (const float*)d_in[7];
    const float* Wv  = (const float*)d_in[8];
    const float* bv  = (const float*)d_in[9];
    const float* Wo  = (const float*)d_in[10];
    const float* bo  = (const float*)d_in[11];
    const float* g1  = (const float*)d_in[12];
    const float* b1n = (const float*)d_in[13];
    const float* g2  = (const float*)d_in[14];
    const float* b2n = (const float*)d_in[15];
    const float* W1  = (const float*)d_in[16];
    const float* bf1 = (const float*)d_in[17];
    const float* W2  = (const float*)d_in[18];
    const float* bf2 = (const float*)d_in[19];

    char* ws = (char*)d_ws;
    const size_t MB = 1024 * 1024;
    u16*   qkvT  = (u16*)(ws + 0);        // Wq^T,Wk^T,Wv^T bf16 contiguous: (3072,1024), 6 MB
    u16*   WoT   = (u16*)(ws + 6 * MB);   // 2 MB
    u16*   W1T   = (u16*)(ws + 8 * MB);   // (4096,1024), 8 MB
    u16*   W2T   = (u16*)(ws + 16 * MB);  // (1024,4096), 8 MB
    u16*   h     = (u16*)(ws + 24 * MB);  // LN output bf16 (reused as h2), 8 MB
    u16*   qkvh  = (u16*)(ws + 32 * MB);  // Q,K in (B,H,T,DH); V in (B,H,DH,T), 3x8 MB
    u16*   attnC = (u16*)(ws + 56 * MB);  // attention out bf16 (B,T,D), 8 MB
    float* x2    = (float*)(ws + 64 * MB);// f32 residual stream, 16 MB
    u16*   ffnh  = (u16*)(ws + 80 * MB);  // bf16 (4096,4096), 32 MB   -> total 112 MB

    // weight transposes + bf16 convert (B^T layout for the GEMMs)
    tr_k<<<dim3(16, 16), 256, 0, stream>>>(Wq, qkvT,               1024, 1024);
    tr_k<<<dim3(16, 16), 256, 0, stream>>>(Wk, qkvT + 1 * MB,      1024, 1024);
    tr_k<<<dim3(16, 16), 256, 0, stream>>>(Wv, qkvT + 2 * MB,      1024, 1024);
    tr_k<<<dim3(16, 16), 256, 0, stream>>>(Wo, WoT,                1024, 1024);
    tr_k<<<dim3(64, 16), 256, 0, stream>>>(W1, W1T,                1024, 4096);
    tr_k<<<dim3(16, 64), 256, 0, stream>>>(W2, W2T,                4096, 1024);

    ln_k<<<4096, 256, 0, stream>>>(x, g1, b1n, h);
    gemm_k<EPI_QKV><<<dim3(24, 32), 256, 0, stream>>>(
        h, qkvT, qkvh, 4096, 3072, 1024, bq, bk, bv, nullptr, cosp, sinp);
    fattn_k<<<dim3(32, 32), 256, 0, stream>>>(qkvh, qkvh + HBUF, qkvh + 2 * HBUF, attnC);
    gemm_k<EPI_RESF><<<dim3(8, 32), 256, 0, stream>>>(
        attnC, WoT, x2, 4096, 1024, 1024, bo, nullptr, nullptr, x, nullptr, nullptr);
    ln_k<<<4096, 256, 0, stream>>>(x2, g2, b2n, h);
    gemm_k<EPI_GELU><<<dim3(32, 32), 256, 0, stream>>>(
        h, W1T, ffnh, 4096, 4096, 1024, bf1, nullptr, nullptr, nullptr, nullptr, nullptr);
    gemm_k<EPI_RES2><<<dim3(8, 32), 256, 0, stream>>>(
        ffnh, W2T, (float*)d_out, 4096, 1024, 4096, bf2, nullptr, nullptr, x2, nullptr, nullptr);
}

// Round 5
// 468.731 us; speedup vs baseline: 5.9392x; 1.1555x over previous
//
#include <hip/hip_runtime.h>

typedef unsigned short u16;
typedef unsigned int   u32;
typedef __attribute__((ext_vector_type(8))) short          short8;
typedef __attribute__((ext_vector_type(4))) float          f32x4;
typedef __attribute__((ext_vector_type(8))) unsigned short u16x8;
typedef __attribute__((ext_vector_type(4))) unsigned short u16x4;

#define T_SEQ  2048
#define DMODEL 1024
#define NHEAD  16
#define DHEAD  64
#define HBUF   4194304   // elems in one (B,H,T,DH) buffer = 2*16*2048*64

__device__ __forceinline__ float bf2f(u16 u) {
    u32 i = ((u32)u) << 16; float f; __builtin_memcpy(&f, &i, 4); return f;
}
__device__ __forceinline__ u16 f2bf(float f) {
    u32 x; __builtin_memcpy(&x, &f, 4);
    return (u16)((x + 0x7FFFu + ((x >> 16) & 1u)) >> 16);   // RNE
}

// async global->LDS, 16B per lane; LDS dest = wave-uniform base + lane*16 (m97/m104)
__device__ __forceinline__ void gld16(const u16* g, u16* l) {
    auto gp = reinterpret_cast<const __attribute__((address_space(1))) u32*>(
        reinterpret_cast<uintptr_t>(g));
    auto lp = reinterpret_cast<__attribute__((address_space(3))) u32*>(
        (u32)reinterpret_cast<uintptr_t>(l));
    __builtin_amdgcn_global_load_lds(gp, lp, 16, 0, 0);
}

// ---------------- LayerNorm (f32 in -> bf16 out): one block per row of 1024 ----------------
__global__ __launch_bounds__(256) void ln_k(const float* __restrict__ x,
                                            const float* __restrict__ g,
                                            const float* __restrict__ bb,
                                            u16* __restrict__ out)
{
    int row = blockIdx.x, tid = threadIdx.x;
    const float* xr = x + (size_t)row * DMODEL;
    f32x4 v = *(const f32x4*)(xr + tid * 4);
    float s  = v[0] + v[1] + v[2] + v[3];
    float s2 = v[0]*v[0] + v[1]*v[1] + v[2]*v[2] + v[3]*v[3];
    #pragma unroll
    for (int o = 32; o; o >>= 1) { s += __shfl_xor(s, o); s2 += __shfl_xor(s2, o); }
    __shared__ float rs[4], rq[4];
    if ((tid & 63) == 0) { rs[tid >> 6] = s; rq[tid >> 6] = s2; }
    __syncthreads();
    float S  = rs[0] + rs[1] + rs[2] + rs[3];
    float S2 = rq[0] + rq[1] + rq[2] + rq[3];
    float mean = S * (1.f / DMODEL);
    float var  = S2 * (1.f / DMODEL) - mean * mean;
    float rstd = rsqrtf(var + 1e-5f);
    f32x4 gv = *(const f32x4*)(g + tid * 4);
    f32x4 bv = *(const f32x4*)(bb + tid * 4);
    u16x4 o;
    #pragma unroll
    for (int e = 0; e < 4; e++)
        o[e] = f2bf((v[e] - mean) * rstd * gv[e] + bv[e]);
    *(u16x4*)(out + (size_t)row * DMODEL + tid * 4) = o;
}

// -------- 64x64-tile transpose + f32->bf16 convert: out[c][r] = bf16(in[r][c]) --------
__device__ __forceinline__ void tr_body(const float* __restrict__ in,
                                        u16* __restrict__ out, int R, int C,
                                        int bx, int by, int tid)
{
    __shared__ u16 s[64][72];
    int c0 = bx * 64, r0 = by * 64;
    #pragma unroll
    for (int p = 0; p < 2; p++) {
        int r = (tid >> 3) + p * 32, cq = (tid & 7) * 8;
        const float* ip = in + (size_t)(r0 + r) * C + c0 + cq;
        f32x4 a = *(const f32x4*)ip;
        f32x4 b = *(const f32x4*)(ip + 4);
        u16x8 o;
        #pragma unroll
        for (int e = 0; e < 4; e++) { o[e] = f2bf(a[e]); o[4 + e] = f2bf(b[e]); }
        *(u16x8*)(&s[r][cq]) = o;
    }
    __syncthreads();
    int oc = tid >> 2, kq = (tid & 3) * 16;
    u16 tmp[16] __attribute__((aligned(16)));
    #pragma unroll
    for (int e = 0; e < 16; e++) tmp[e] = s[kq + e][oc];
    u16* op = out + (size_t)(c0 + oc) * R + r0 + kq;
    *(u16x8*)op       = *(const u16x8*)(&tmp[0]);
    *(u16x8*)(op + 8) = *(const u16x8*)(&tmp[8]);
}

__global__ __launch_bounds__(256) void tr_k(const float* __restrict__ in,
                                            u16* __restrict__ out, int R, int C)
{
    tr_body(in, out, R, C, blockIdx.x, blockIdx.y, threadIdx.x);
}

// merged transpose for the four 1024x1024 weights (one launch instead of four)
__global__ __launch_bounds__(256) void tr4_k(const float* __restrict__ w0, const float* __restrict__ w1,
                                             const float* __restrict__ w2, const float* __restrict__ w3,
                                             u16* __restrict__ o0, u16* __restrict__ o1,
                                             u16* __restrict__ o2, u16* __restrict__ o3)
{
    int z = blockIdx.z;
    const float* in = (z == 0) ? w0 : (z == 1) ? w1 : (z == 2) ? w2 : w3;
    u16* out        = (z == 0) ? o0 : (z == 1) ? o1 : (z == 2) ? o2 : o3;
    tr_body(in, out, 1024, 1024, blockIdx.x, blockIdx.y, threadIdx.x);
}

// ---------------- MFMA GEMM: C = A[M,K] @ Bt[N,K]^T (bf16 in, f32 acc), fused epilogues ----------------
// m97 pattern: global_load_lds width=16 into UNPADDED [BM][32]/[128][32] LDS tiles.
// BM=128: 2x2 waves of 64x64. BM=64: 2x2 waves of 32x64 (more blocks for narrow-N GEMMs).
constexpr int EPI_QKV = 0, EPI_RESF = 1, EPI_GELU = 2, EPI_RES2 = 3;

template<int EPI, int BM>
__global__ __launch_bounds__(256) void gemm_k(
    const u16* __restrict__ A, const u16* __restrict__ Bt, void* __restrict__ outv,
    int M, int N, int K,
    const float* __restrict__ b0, const float* __restrict__ b1, const float* __restrict__ b2,
    const float* __restrict__ resid,
    const float* __restrict__ cosp, const float* __restrict__ sinp)
{
    constexpr int MI = BM / 32;          // i-tiles per wave
    __shared__ u16 As[BM * 32];
    __shared__ u16 Bs[128 * 32];
    int tid = threadIdx.x;
    int n0 = blockIdx.x * 128, m0 = blockIdx.y * BM;
    int wave = tid >> 6, lane = tid & 63, lm = lane & 15, ko = lane >> 4;
    int wm = (wave & 1) * (BM / 2), wn = (wave >> 1) * 64;
    f32x4 acc[MI][4];
    #pragma unroll
    for (int i = 0; i < MI; i++)
        #pragma unroll
        for (int j = 0; j < 4; j++) acc[i][j] = (f32x4){0.f, 0.f, 0.f, 0.f};

    int srow = wave * 16 + (lane >> 2);
    int scol = (lane & 3) * 8;
    const u16* Ag = A  + (size_t)(m0 + srow) * K + scol;
    const u16* Bg = Bt + (size_t)(n0 + srow) * K + scol;
    u16* Al = &As[wave * 16 * 32];    // wave-uniform LDS bases
    u16* Bl = &Bs[wave * 16 * 32];

    for (int kt = 0; kt < K; kt += 32) {
        __syncthreads();
        gld16(Ag, Al);
        if constexpr (BM == 128) gld16(Ag + 64 * (size_t)K, Al + 64 * 32);
        gld16(Bg,                  Bl);
        gld16(Bg + 64 * (size_t)K, Bl + 64 * 32);
        Ag += 32; Bg += 32;
        __syncthreads();
        short8 af[MI], bf[4];
        #pragma unroll
        for (int i = 0; i < MI; i++) af[i] = *(const short8*)(&As[(wm + i * 16 + lm) * 32 + ko * 8]);
        #pragma unroll
        for (int j = 0; j < 4; j++) bf[j] = *(const short8*)(&Bs[(wn + j * 16 + lm) * 32 + ko * 8]);
        #pragma unroll
        for (int i = 0; i < MI; i++)
            #pragma unroll
            for (int j = 0; j < 4; j++)
                acc[i][j] = __builtin_amdgcn_mfma_f32_16x16x32_bf16(af[i], bf[j], acc[i][j], 0, 0, 0);
    }

    // epilogue — C/D layout: col = lane&15, row = (lane>>4)*4 + reg  [m89/m91]
    #pragma unroll
    for (int i = 0; i < MI; i++) {
        #pragma unroll
        for (int j = 0; j < 4; j++) {
            int n = n0 + wn + j * 16 + lm;
            #pragma unroll
            for (int r = 0; r < 4; r++) {
                int m = m0 + wm + i * 16 + ko * 4 + r;
                float v = acc[i][j][r];
                if constexpr (EPI == EPI_QKV) {
                    int which = n >> 10, nn = n & 1023;
                    const float* bp = (which == 0) ? b0 : (which == 1 ? b1 : b2);
                    v += bp[nn];
                    float vp = __shfl_xor(v, 1);          // RoPE partner (col^1), all lanes
                    int bi = m >> 11, t = m & 2047, hh = nn >> 6, d = nn & 63;
                    u16* outp = (u16*)outv + (size_t)which * HBUF;
                    if (which < 2) {
                        size_t oidx = ((size_t)((bi * NHEAD + hh) * T_SEQ + t)) * DHEAD + d;
                        size_t ci = ((size_t)((bi * NHEAD + hh) * T_SEQ + t)) * 32 + (d >> 1);
                        float c = cosp[ci], sn = sinp[ci];
                        float o = (d & 1) ? (vp * sn + v * c) : (v * c - vp * sn);
                        if (which == 0) o *= 0.125f;      // 1/sqrt(DH) folded into Q
                        outp[oidx] = f2bf(o);
                    } else {
                        // V stored TRANSPOSED per head: (B,H,DH,T) for flash-attn B-frags
                        size_t oidx = ((size_t)((bi * NHEAD + hh) * DHEAD + d)) * T_SEQ + t;
                        outp[oidx] = f2bf(v);
                    }
                } else if constexpr (EPI == EPI_RESF) {
                    v += b0[n] + resid[(size_t)m * N + n];
                    ((float*)outv)[(size_t)m * N + n] = v;   // f32 residual stream
                } else if constexpr (EPI == EPI_GELU) {
                    v += b0[n];
                    float gl = 0.5f * v * (1.f + erff(v * 0.70710678118654752f));
                    ((u16*)outv)[(size_t)m * N + n] = f2bf(gl);
                } else { // EPI_RES2 -> f32 final output
                    v += b0[n] + resid[(size_t)m * N + n];
                    ((float*)outv)[(size_t)m * N + n] = v;
                }
            }
        }
    }
}

// ---------------- flash attention (MFMA), balanced + prefetched ----------------
// Block handles TWO q-tiles (qt and 31-qt): exactly 33 K-iterations per block.
// Q: (B,H,T,DH) bf16 (pre-scaled 1/8); K: (B,H,T,DH); Vt: (B,H,DH,T); out: (B,T,D)
__device__ __forceinline__ void attn_step(
    bool diag, int wave, int lm, int ko,
    short8 aq0, short8 aq1,
    const u16 (*sK)[72], const u16 (*sV)[72], u16 (*sPw)[72],
    f32x4* oacc, float* mr, float* lr)
{
    // S = Q K^T for this wave's 16 rows x 64 cols
    f32x4 sacc[4];
    #pragma unroll
    for (int j = 0; j < 4; j++) {
        short8 bk0 = *(const short8*)(&sK[j * 16 + lm][ko * 8]);
        short8 bk1 = *(const short8*)(&sK[j * 16 + lm][32 + ko * 8]);
        f32x4 z = (f32x4){0.f, 0.f, 0.f, 0.f};
        z = __builtin_amdgcn_mfma_f32_16x16x32_bf16(aq0, bk0, z, 0, 0, 0);
        z = __builtin_amdgcn_mfma_f32_16x16x32_bf16(aq1, bk1, z, 0, 0, 0);
        sacc[j] = z;
    }
    if (diag) {  // causal mask on diagonal tile: col > row -> -inf
        #pragma unroll
        for (int j = 0; j < 4; j++)
            #pragma unroll
            for (int r = 0; r < 4; r++)
                if (j * 16 + lm > wave * 16 + ko * 4 + r) sacc[j][r] = -1e30f;
    }

    // online softmax (rows = ko*4+r, replicated across 16-lane group)
    float vmax[4], rsum[4], alpha[4];
    #pragma unroll
    for (int r = 0; r < 4; r++)
        vmax[r] = fmaxf(fmaxf(sacc[0][r], sacc[1][r]), fmaxf(sacc[2][r], sacc[3][r]));
    #pragma unroll
    for (int o = 1; o < 16; o <<= 1)
        #pragma unroll
        for (int r = 0; r < 4; r++) vmax[r] = fmaxf(vmax[r], __shfl_xor(vmax[r], o));
    #pragma unroll
    for (int r = 0; r < 4; r++) {
        float mn = fmaxf(mr[r], vmax[r]);
        alpha[r] = __expf(mr[r] - mn);
        mr[r] = mn;
        rsum[r] = 0.f;
    }
    u16 pb[4][4];
    #pragma unroll
    for (int j = 0; j < 4; j++)
        #pragma unroll
        for (int r = 0; r < 4; r++) {
            float p = __expf(sacc[j][r] - mr[r]);
            rsum[r] += p;
            pb[j][r] = f2bf(p);
        }
    #pragma unroll
    for (int o = 1; o < 16; o <<= 1)
        #pragma unroll
        for (int r = 0; r < 4; r++) rsum[r] += __shfl_xor(rsum[r], o);
    #pragma unroll
    for (int r = 0; r < 4; r++) lr[r] = lr[r] * alpha[r] + rsum[r];
    #pragma unroll
    for (int j = 0; j < 4; j++)
        #pragma unroll
        for (int r = 0; r < 4; r++) oacc[j][r] *= alpha[r];

    // P -> LDS (C/D -> A-operand layout); wave-private region, in-wave order => no barrier
    #pragma unroll
    for (int j = 0; j < 4; j++)
        #pragma unroll
        for (int r = 0; r < 4; r++) sPw[ko * 4 + r][j * 16 + lm] = pb[j][r];

    // O += P V  (B-frag rows are sV[d][kpos] — contiguous)
    #pragma unroll
    for (int ks = 0; ks < 2; ks++) {
        short8 ap = *(const short8*)(&sPw[lm][ks * 32 + ko * 8]);
        #pragma unroll
        for (int j = 0; j < 4; j++) {
            short8 bv = *(const short8*)(&sV[j * 16 + lm][ks * 32 + ko * 8]);
            oacc[j] = __builtin_amdgcn_mfma_f32_16x16x32_bf16(ap, bv, oacc[j], 0, 0, 0);
        }
    }
}

__global__ __launch_bounds__(256) void fattn_k(const u16* __restrict__ Q,
                                               const u16* __restrict__ K,
                                               const u16* __restrict__ Vt,
                                               u16* __restrict__ out)
{
    __shared__ u16 sQP[4][16][72];      // Q staging (prologue) then per-wave P tile
    __shared__ u16 sK[64][72];
    __shared__ u16 sV[64][72];          // [d][kpos]
    int tid = threadIdx.x;
    int qtA = blockIdx.x;               // grid.x = 16
    int qtB = 31 - qtA;                 // pairing: every block does 33 K-iterations
    int bh = blockIdx.y;
    int wave = tid >> 6, lane = tid & 63, lm = lane & 15, ko = lane >> 4;
    int bi = bh >> 4, hh = bh & 15;

    const u16* Kb = K  + (size_t)bh * T_SEQ * DHEAD;
    const u16* Vb = Vt + (size_t)bh * DHEAD * T_SEQ;
    u16* sQf = &sQP[0][0][0];
    int srow = tid >> 2, scol = (tid & 3) * 16;

    // prologue: Q fragments for both tiles via LDS staging
    short8 aqA0, aqA1, aqB0, aqB1;
    {
        const u16* QbA = Q + ((size_t)bh * T_SEQ + qtA * 64) * DHEAD + (size_t)srow * DHEAD + scol;
        *(u16x8*)(&sQf[srow * 72 + scol])     = *(const u16x8*)QbA;
        *(u16x8*)(&sQf[srow * 72 + scol + 8]) = *(const u16x8*)(QbA + 8);
        __syncthreads();
        aqA0 = *(const short8*)(&sQf[(wave * 16 + lm) * 72 + ko * 8]);
        aqA1 = *(const short8*)(&sQf[(wave * 16 + lm) * 72 + 32 + ko * 8]);
        __syncthreads();
        const u16* QbB = Q + ((size_t)bh * T_SEQ + qtB * 64) * DHEAD + (size_t)srow * DHEAD + scol;
        *(u16x8*)(&sQf[srow * 72 + scol])     = *(const u16x8*)QbB;
        *(u16x8*)(&sQf[srow * 72 + scol + 8]) = *(const u16x8*)(QbB + 8);
        __syncthreads();
        aqB0 = *(const short8*)(&sQf[(wave * 16 + lm) * 72 + ko * 8]);
        aqB1 = *(const short8*)(&sQf[(wave * 16 + lm) * 72 + 32 + ko * 8]);
    }

    f32x4 oA[4], oB[4];
    float mA[4], lA[4], mB[4], lB[4];
    #pragma unroll
    for (int j = 0; j < 4; j++) { oA[j] = (f32x4){0,0,0,0}; oB[j] = (f32x4){0,0,0,0}; }
    #pragma unroll
    for (int r = 0; r < 4; r++) { mA[r] = -1e30f; lA[r] = 0.f; mB[r] = -1e30f; lB[r] = 0.f; }

    int nA = qtA + 1, n = nA + qtB + 1;   // = 33

    // prefetch i=0 (tile A, kt=0) K/V chunk into registers
    u16x8 pk0, pk1, pv0, pv1;
    {
        const u16* kp = Kb + (size_t)srow * DHEAD + scol;
        pk0 = *(const u16x8*)kp; pk1 = *(const u16x8*)(kp + 8);
        const u16* vp = Vb + (size_t)srow * T_SEQ + scol;
        pv0 = *(const u16x8*)vp; pv1 = *(const u16x8*)(vp + 8);
    }

    for (int i = 0; i < n; i++) {
        bool isA = i < nA;
        int kt = isA ? i : i - nA;

        __syncthreads();                       // prev iter done reading sK/sV
        *(u16x8*)(&sK[srow][scol])     = pk0;
        *(u16x8*)(&sK[srow][scol + 8]) = pk1;
        *(u16x8*)(&sV[srow][scol])     = pv0;
        *(u16x8*)(&sV[srow][scol + 8]) = pv1;
        __syncthreads();

        if (i + 1 < n) {                       // prefetch next chunk (overlaps compute)
            int kt2 = (i + 1 < nA) ? i + 1 : i + 1 - nA;
            const u16* kp = Kb + ((size_t)(kt2 * 64 + srow)) * DHEAD + scol;
            pk0 = *(const u16x8*)kp; pk1 = *(const u16x8*)(kp + 8);
            const u16* vp = Vb + (size_t)srow * T_SEQ + kt2 * 64 + scol;
            pv0 = *(const u16x8*)vp; pv1 = *(const u16x8*)(vp + 8);
        }

        if (isA)
            attn_step(kt == qtA, wave, lm, ko, aqA0, aqA1, sK, sV, sQP[wave], oA, mA, lA);
        else
            attn_step(kt == qtB, wave, lm, ko, aqB0, aqB1, sK, sV, sQP[wave], oB, mB, lB);
    }

    #pragma unroll
    for (int r = 0; r < 4; r++) { lA[r] = 1.f / lA[r]; lB[r] = 1.f / lB[r]; }
    int qrowA = qtA * 64 + wave * 16, qrowB = qtB * 64 + wave * 16;
    #pragma unroll
    for (int j = 0; j < 4; j++)
        #pragma unroll
        for (int r = 0; r < 4; r++) {
            out[((size_t)(bi * T_SEQ) + qrowA + ko * 4 + r) * DMODEL + hh * DHEAD + j * 16 + lm]
                = f2bf(oA[j][r] * lA[r]);
            out[((size_t)(bi * T_SEQ) + qrowB + ko * 4 + r) * DMODEL + hh * DHEAD + j * 16 + lm]
                = f2bf(oB[j][r] * lB[r]);
        }
}

// ---------------- host launch ----------------
extern "C" void kernel_launch(void* const* d_in, const int* in_sizes, int n_in,
                              void* d_out, int out_size, void* d_ws, size_t ws_size,
                              hipStream_t stream)
{
    (void)in_sizes; (void)n_in; (void)out_size; (void)ws_size;
    const float* x    = (const float*)d_in[0];
    const float* cosp = (const float*)d_in[1];
    const float* sinp = (const float*)d_in[2];
    // d_in[3] causal_mask: unused (recomputed from indices)
    const float* Wq  = (const float*)d_in[4];
    const float* bq  = (const float*)d_in[5];
    const float* Wk  = (const float*)d_in[6];
    const float* bk  = (const float*)d_in[7];
    const float* Wv  = (const float*)d_in[8];
    const float* bv  = (const float*)d_in[9];
    const float* Wo  = (const float*)d_in[10];
    const float* bo  = (const float*)d_in[11];
    const float* g1  = (const float*)d_in[12];
    const float* b1n = (const float*)d_in[13];
    const float* g2  = (const float*)d_in[14];
    const float* b2n = (const float*)d_in[15];
    const float* W1  = (const float*)d_in[16];
    const float* bf1 = (const float*)d_in[17];
    const float* W2  = (const float*)d_in[18];
    const float* bf2 = (const float*)d_in[19];

    char* ws = (char*)d_ws;
    const size_t MB = 1024 * 1024;
    u16*   qkvT  = (u16*)(ws + 0);        // Wq^T,Wk^T,Wv^T bf16 contiguous: (3072,1024), 6 MB
    u16*   WoT   = (u16*)(ws + 6 * MB);   // 2 MB
    u16*   W1T   = (u16*)(ws + 8 * MB);   // (4096,1024), 8 MB
    u16*   W2T   = (u16*)(ws + 16 * MB);  // (1024,4096), 8 MB
    u16*   h     = (u16*)(ws + 24 * MB);  // LN output bf16 (reused as h2), 8 MB
    u16*   qkvh  = (u16*)(ws + 32 * MB);  // Q,K in (B,H,T,DH); V in (B,H,DH,T), 3x8 MB
    u16*   attnC = (u16*)(ws + 56 * MB);  // attention out bf16 (B,T,D), 8 MB
    float* x2    = (float*)(ws + 64 * MB);// f32 residual stream, 16 MB
    u16*   ffnh  = (u16*)(ws + 80 * MB);  // bf16 (4096,4096), 32 MB   -> total 112 MB

    // weight transposes + bf16 convert (B^T layout for the GEMMs)
    tr4_k<<<dim3(16, 16, 4), 256, 0, stream>>>(Wq, Wk, Wv, Wo,
                                               qkvT, qkvT + 1 * MB, qkvT + 2 * MB, WoT);
    tr_k<<<dim3(64, 16), 256, 0, stream>>>(W1, W1T, 1024, 4096);
    tr_k<<<dim3(16, 64), 256, 0, stream>>>(W2, W2T, 4096, 1024);

    ln_k<<<4096, 256, 0, stream>>>(x, g1, b1n, h);
    gemm_k<EPI_QKV, 128><<<dim3(24, 32), 256, 0, stream>>>(
        h, qkvT, qkvh, 4096, 3072, 1024, bq, bk, bv, nullptr, cosp, sinp);
    fattn_k<<<dim3(16, 32), 256, 0, stream>>>(qkvh, qkvh + HBUF, qkvh + 2 * HBUF, attnC);
    gemm_k<EPI_RESF, 64><<<dim3(8, 64), 256, 0, stream>>>(
        attnC, WoT, x2, 4096, 1024, 1024, bo, nullptr, nullptr, x, nullptr, nullptr);
    ln_k<<<4096, 256, 0, stream>>>(x2, g2, b2n, h);
    gemm_k<EPI_GELU, 128><<<dim3(32, 32), 256, 0, stream>>>(
        h, W1T, ffnh, 4096, 4096, 1024, bf1, nullptr, nullptr, nullptr, nullptr, nullptr);
    gemm_k<EPI_RES2, 64><<<dim3(8, 64), 256, 0, stream>>>(
        ffnh, W2T, (float*)d_out, 4096, 1024, 4096, bf2, nullptr, nullptr, x2, nullptr, nullptr);
}